// Round 9
// baseline (2733.275 us; speedup 1.0000x reference)
//
#include <hip/hip_runtime.h>
#include <hip/hip_fp16.h>

// Masked LSTM, T=512 B=64 D=512 H=512 — fused persistent kernel, DUAL-STREAM.
// Each of 128 blocks owns TWO batch-groups (A: batches gA*8.., B: +32) with the
// SAME j-slice (rank) -> same W_hh/W_ih LDS slices serve both. Streams alternate:
// while A's inter-block exchange propagates, B computes, and vice versa -> each
// flag spin lands ~a-compute-phase after the flags were posted (single poll).
// Per stream per step: spin -> stage h (LLC->LDS) + issue x(ts+1) loads (T14) ->
// MFMA 8x(h@Whh) + 8x(xs@Wih) dual-chain -> part (lanes<32; m<8 only) ->
// epilogue (tid<128) -> publish (u64 packed fp16, relaxed agent) -> drain ->
// flag -> xs ds_write + out stores in the shadow.
// LDS fit: hl 8 rows (A-frag am=lane&7 duplicates D rows 8-15, discarded),
// part [8][8][16]. Total 162,176 B <= 160 KiB.

#define T_DIM 512
#define B_DIM 64
#define D_DIM 512
#define H_DIM 512

#define BPG 32
#define NBLK 128
#define NTHR 512
#define WS 520                  // LDS row stride in fp16 elements (512 + 8 pad)

typedef __attribute__((ext_vector_type(8))) _Float16 half8;
typedef __attribute__((ext_vector_type(2))) __fp16 fp16x2;
typedef __attribute__((ext_vector_type(4))) float float4v;

#define AT_LD_I(p)    __hip_atomic_load((p), __ATOMIC_RELAXED, __HIP_MEMORY_SCOPE_AGENT)
#define AT_ST_I(p, v) __hip_atomic_store((p), (v), __ATOMIC_RELAXED, __HIP_MEMORY_SCOPE_AGENT)
#define AT_LD64(p)    __hip_atomic_load((p), __ATOMIC_RELAXED, __HIP_MEMORY_SCOPE_AGENT)
#define AT_ST64(p, v) __hip_atomic_store((p), (v), __ATOMIC_RELAXED, __HIP_MEMORY_SCOPE_AGENT)

__device__ __forceinline__ float sigf(float x) { return 1.0f / (1.0f + __expf(-x)); }
__device__ __forceinline__ float tanhfast(float x) { return 2.0f / (1.0f + __expf(-2.0f * x)) - 1.0f; }
__device__ __forceinline__ unsigned short f2h(float x) {
  return __builtin_bit_cast(unsigned short, (_Float16)x);
}
__device__ __forceinline__ unsigned pk2h(float a, float b) {
  fp16x2 h = __builtin_amdgcn_cvt_pkrtz(a, b);
  return __builtin_bit_cast(unsigned, h);
}

#define SPIN(slots, tgt)                                          \
  do {                                                            \
    if (tid < 64) {                                               \
      int v_;                                                     \
      do {                                                        \
        v_ = (tid < BPG) ? AT_LD_I(&(slots)[tid]) : (tgt);        \
        if (__all(v_ >= (tgt))) break;                            \
        __builtin_amdgcn_s_sleep(1);                              \
      } while (true);                                             \
    }                                                             \
    __syncthreads();                                              \
    __asm__ volatile("" ::: "memory");                            \
  } while (0)

// ---------------------------------------------------------------- fused LSTM
__global__ __launch_bounds__(NTHR) void lstm_seq(
    const float* __restrict__ inputs, const float* __restrict__ mask,
    const float* __restrict__ h0, const float* __restrict__ Whh,
    const float* __restrict__ Wih, const float* __restrict__ b_ih,
    const float* __restrict__ b_hh,
    float* __restrict__ out, unsigned short* __restrict__ hbuf,
    int* slot_base) {
  extern __shared__ char smemc[];
  unsigned short* Wl  = (unsigned short*)smemc;    // W_hh [64][WS] = 66560 B
  unsigned short* Xw  = Wl + 64 * WS;              // W_ih [64][WS] = 66560 B
  unsigned short* hl  = Xw + 64 * WS;              // h stage [8][WS] = 8320 B (shared A/B)
  unsigned short* xsA = hl + 8 * WS;               // x stage A [8][WS] = 8320 B
  unsigned short* xsB = xsA + 8 * WS;              // x stage B [8][WS] = 8320 B
  float* part = (float*)(xsB + 8 * WS);            // [8 waves][8 m][16 n] = 4096 B
  // total 162,176 B

  const int tid = threadIdx.x;
  const int blk = blockIdx.x;
  const int gA = blk & 3;
  const int rank = blk >> 2;              // 0..31
  const int bbA = gA * 8;
  const int bbB = bbA + 32;
  const int jbase = rank * 16;
  int* slotsA = (int*)((char*)slot_base + gA * 128);
  int* slotsB = (int*)((char*)slot_base + (gA + 4) * 128);

  // ---- W_hh + W_ih slices -> LDS fp16. r = q*16 + jl <-> global row q*512+jbase+jl.
  for (int idx = tid; idx < 64 * 128; idx += NTHR) {
    int r = idx >> 7;
    int k4 = (idx & 127) << 2;
    int grow = (r >> 4) * H_DIM + jbase + (r & 15);
    float4 wv = *(const float4*)(Whh + (size_t)grow * H_DIM + k4);
    *(uint2*)(Wl + r * WS + k4) = make_uint2(pk2h(wv.x, wv.y), pk2h(wv.z, wv.w));
    float4 xv = *(const float4*)(Wih + (size_t)grow * D_DIM + k4);
    *(uint2*)(Xw + r * WS + k4) = make_uint2(pk2h(xv.x, xv.y), pk2h(xv.z, xv.w));
  }

  const int eb = tid >> 4, ejl = tid & 15;   // tid<128: (batch 0..7, h-dim 0..15)
  const int bglobA = bbA + eb;
  const int bglobB = bbB + eb;
  const int jglob = jbase + ejl;
  float h0vA = 0.f, cvalA = 0.f, mvalA = 1.f;
  float h0vB = 0.f, cvalB = 0.f, mvalB = 1.f;
  float bi_ = 0.f, bf_ = 0.f, bg_ = 0.f, bo_ = 0.f;
  if (tid < 128) {
    h0vA = h0[bglobA * H_DIM + jglob];  cvalA = h0vA;
    h0vB = h0[bglobB * H_DIM + jglob];  cvalB = h0vB;
    bi_ = b_ih[0 * H_DIM + jglob] + b_hh[0 * H_DIM + jglob];
    bf_ = b_ih[1 * H_DIM + jglob] + b_hh[1 * H_DIM + jglob];
    bg_ = b_ih[2 * H_DIM + jglob] + b_hh[2 * H_DIM + jglob];
    bo_ = b_ih[3 * H_DIM + jglob] + b_hh[3 * H_DIM + jglob];
    mvalA = mask[bglobA];
    mvalB = mask[bglobB];
  }

  // per-thread x-stage geometry: thread covers 4 (row, col-u32) slots of an 8x512 slab
  const int xr0r = tid >> 8,           xc = tid & 255;
  const int xr1r = (tid + 512) >> 8;
  const int xr2r = (tid + 1024) >> 8;
  const int xr3r = (tid + 1536) >> 8;

  // ---- publish h0 (both streams) into buffer 0 as u64 packed fp16
  {
    int mbA = (tid < 128) ? (int)f2h(h0vA) : 0;
    int mbB = (tid < 128) ? (int)f2h(h0vB) : 0;
    int a1 = __shfl_down(mbA, 1, 64), a2 = __shfl_down(mbA, 2, 64), a3 = __shfl_down(mbA, 3, 64);
    int b1 = __shfl_down(mbB, 1, 64), b2 = __shfl_down(mbB, 2, 64), b3 = __shfl_down(mbB, 3, 64);
    if (tid < 128 && ((ejl & 3) == 0)) {
      unsigned long long uA = ((unsigned long long)(((unsigned)a2) | ((unsigned)a3 << 16)) << 32) |
                              (((unsigned)mbA) | ((unsigned)a1 << 16));
      unsigned long long uB = ((unsigned long long)(((unsigned)b2) | ((unsigned)b3 << 16)) << 32) |
                              (((unsigned)mbB) | ((unsigned)b1 << 16));
      AT_ST64((unsigned long long*)hbuf + bglobA * 128 + (jglob >> 2), uA);
      AT_ST64((unsigned long long*)hbuf + bglobB * 128 + (jglob >> 2), uB);
    }
  }
  __syncthreads();   // drains vmcnt(0): publishes at coherence point
  if (tid == 0) { AT_ST_I(&slotsA[rank], 1); AT_ST_I(&slotsB[rank], 1); }

  // ---- bootstrap xs: stage x(0) for both streams
  {
    const float* xa = inputs + (size_t)bbA * D_DIM;
    const float* xb = inputs + (size_t)bbB * D_DIM;
    float2 t0 = *(const float2*)(xa + (size_t)xr0r * D_DIM + xc * 2);
    float2 t1 = *(const float2*)(xa + (size_t)xr1r * D_DIM + xc * 2);
    float2 t2 = *(const float2*)(xa + (size_t)xr2r * D_DIM + xc * 2);
    float2 t3 = *(const float2*)(xa + (size_t)xr3r * D_DIM + xc * 2);
    float2 s0 = *(const float2*)(xb + (size_t)xr0r * D_DIM + xc * 2);
    float2 s1 = *(const float2*)(xb + (size_t)xr1r * D_DIM + xc * 2);
    float2 s2 = *(const float2*)(xb + (size_t)xr2r * D_DIM + xc * 2);
    float2 s3 = *(const float2*)(xb + (size_t)xr3r * D_DIM + xc * 2);
    ((unsigned*)xsA)[xr0r * (WS / 2) + xc] = pk2h(t0.x, t0.y);
    ((unsigned*)xsA)[xr1r * (WS / 2) + xc] = pk2h(t1.x, t1.y);
    ((unsigned*)xsA)[xr2r * (WS / 2) + xc] = pk2h(t2.x, t2.y);
    ((unsigned*)xsA)[xr3r * (WS / 2) + xc] = pk2h(t3.x, t3.y);
    ((unsigned*)xsB)[xr0r * (WS / 2) + xc] = pk2h(s0.x, s0.y);
    ((unsigned*)xsB)[xr1r * (WS / 2) + xc] = pk2h(s1.x, s1.y);
    ((unsigned*)xsB)[xr2r * (WS / 2) + xc] = pk2h(s2.x, s2.y);
    ((unsigned*)xsB)[xr3r * (WS / 2) + xc] = pk2h(s3.x, s3.y);
  }

  const int w = tid >> 6;        // wave id
  const int lane = tid & 63;
  const int ks = w >> 2;         // k-split 0..1 (256 k each)
  const int am = lane & 7;       // A row (8 real batches; rows 8-15 duplicated)
  const int koct = (lane >> 4) * 8;
  const int br = (w & 3) * 16 + (lane & 15);   // W row in LDS (gate tile)

  for (int ts = 0; ts < T_DIM; ++ts) {
    const int xts = (ts + 1 < T_DIM) ? ts + 1 : ts;

    // ================= stream A =================
    {
      const unsigned long long* cur =
          (const unsigned long long*)hbuf + (ts & 1) * (B_DIM * H_DIM / 4) + (size_t)bbA * 128;
      unsigned long long* nxt =
          (unsigned long long*)hbuf + ((ts + 1) & 1) * (B_DIM * H_DIM / 4);

      SPIN(slotsA, ts + 1);

      unsigned long long hld0 = AT_LD64(cur + tid);
      unsigned long long hld1 = AT_LD64(cur + tid + NTHR);
      const float* xin = inputs + ((size_t)xts * B_DIM + bbA) * D_DIM;
      float2 a0 = *(const float2*)(xin + (size_t)xr0r * D_DIM + xc * 2);
      float2 a1 = *(const float2*)(xin + (size_t)xr1r * D_DIM + xc * 2);
      float2 a2 = *(const float2*)(xin + (size_t)xr2r * D_DIM + xc * 2);
      float2 a3 = *(const float2*)(xin + (size_t)xr3r * D_DIM + xc * 2);
      ((unsigned long long*)hl)[(tid >> 7) * 130 + (tid & 127)] = hld0;
      { int v2 = tid + NTHR; ((unsigned long long*)hl)[(v2 >> 7) * 130 + (v2 & 127)] = hld1; }
      __syncthreads();

      float4v aH = {0.f, 0.f, 0.f, 0.f}, aX = {0.f, 0.f, 0.f, 0.f};
#pragma unroll
      for (int kc = 0; kc < 8; ++kc) {
        int k = ks * 256 + kc * 32 + koct;
        half8 ah = *(const half8*)((const _Float16*)hl + am * WS + k);
        half8 bh = *(const half8*)((const _Float16*)Wl + br * WS + k);
        aH = __builtin_amdgcn_mfma_f32_16x16x32_f16(ah, bh, aH, 0, 0, 0);
        half8 ax = *(const half8*)((const _Float16*)xsA + am * WS + k);
        half8 bx = *(const half8*)((const _Float16*)Xw + br * WS + k);
        aX = __builtin_amdgcn_mfma_f32_16x16x32_f16(ax, bx, aX, 0, 0, 0);
      }
      float4v acc = aH + aX;
      if (lane < 32) {
#pragma unroll
        for (int reg = 0; reg < 4; ++reg) {
          int m = (lane >> 4) * 4 + reg;
          part[w * 128 + m * 16 + (lane & 15)] = acc[reg];
        }
      }
      __syncthreads();

      float hnew = 0.f;
      if (tid < 128) {
        int o = eb * 16 + ejl;
        float iv = sigf(part[0 * 128 + o] + part[4 * 128 + o] + bi_);
        float fv = sigf(part[1 * 128 + o] + part[5 * 128 + o] + bf_);
        float gv = tanhfast(part[2 * 128 + o] + part[6 * 128 + o] + bg_);
        float ov = sigf(part[3 * 128 + o] + part[7 * 128 + o] + bo_);
        float cn = fv * cvalA + iv * gv;
        float hn = ov * tanhfast(cn);
        hnew = hn * mvalA + h0vA * (1.f - mvalA);
        cvalA = cn * mvalA + h0vA * (1.f - mvalA);
      }
      {
        int mb = (tid < 128) ? (int)f2h(hnew) : 0;
        int n1 = __shfl_down(mb, 1, 64), n2 = __shfl_down(mb, 2, 64), n3 = __shfl_down(mb, 3, 64);
        if (tid < 128 && ((ejl & 3) == 0)) {
          unsigned long long u = ((unsigned long long)(((unsigned)n2) | ((unsigned)n3 << 16)) << 32) |
                                 (((unsigned)mb) | ((unsigned)n1 << 16));
          AT_ST64(nxt + bglobA * 128 + (jglob >> 2), u);
        }
      }
      __syncthreads();   // vmcnt drain -> publishes visible before flag
      if (tid == 0) AT_ST_I(&slotsA[rank], ts + 2);

      // shadow: xs refresh + out stores + mask prefetch
      ((unsigned*)xsA)[xr0r * (WS / 2) + xc] = pk2h(a0.x, a0.y);
      ((unsigned*)xsA)[xr1r * (WS / 2) + xc] = pk2h(a1.x, a1.y);
      ((unsigned*)xsA)[xr2r * (WS / 2) + xc] = pk2h(a2.x, a2.y);
      ((unsigned*)xsA)[xr3r * (WS / 2) + xc] = pk2h(a3.x, a3.y);
      if (tid < 128) {
        out[((size_t)ts * B_DIM + bglobA) * H_DIM + jglob] = hnew;
        if (ts == T_DIM - 1) {
          out[(size_t)T_DIM * B_DIM * H_DIM + bglobA * H_DIM + jglob] = hnew;
          out[(size_t)T_DIM * B_DIM * H_DIM + B_DIM * H_DIM + bglobA * H_DIM + jglob] = cvalA;
        } else {
          mvalA = mask[(ts + 1) * B_DIM + bglobA];
        }
      }
    }

    // ================= stream B =================
    {
      const unsigned long long* cur =
          (const unsigned long long*)hbuf + (ts & 1) * (B_DIM * H_DIM / 4) + (size_t)bbB * 128;
      unsigned long long* nxt =
          (unsigned long long*)hbuf + ((ts + 1) & 1) * (B_DIM * H_DIM / 4);

      SPIN(slotsB, ts + 1);

      unsigned long long hld0 = AT_LD64(cur + tid);
      unsigned long long hld1 = AT_LD64(cur + tid + NTHR);
      const float* xin = inputs + ((size_t)xts * B_DIM + bbB) * D_DIM;
      float2 a0 = *(const float2*)(xin + (size_t)xr0r * D_DIM + xc * 2);
      float2 a1 = *(const float2*)(xin + (size_t)xr1r * D_DIM + xc * 2);
      float2 a2 = *(const float2*)(xin + (size_t)xr2r * D_DIM + xc * 2);
      float2 a3 = *(const float2*)(xin + (size_t)xr3r * D_DIM + xc * 2);
      ((unsigned long long*)hl)[(tid >> 7) * 130 + (tid & 127)] = hld0;
      { int v2 = tid + NTHR; ((unsigned long long*)hl)[(v2 >> 7) * 130 + (v2 & 127)] = hld1; }
      __syncthreads();

      float4v aH = {0.f, 0.f, 0.f, 0.f}, aX = {0.f, 0.f, 0.f, 0.f};
#pragma unroll
      for (int kc = 0; kc < 8; ++kc) {
        int k = ks * 256 + kc * 32 + koct;
        half8 ah = *(const half8*)((const _Float16*)hl + am * WS + k);
        half8 bh = *(const half8*)((const _Float16*)Wl + br * WS + k);
        aH = __builtin_amdgcn_mfma_f32_16x16x32_f16(ah, bh, aH, 0, 0, 0);
        half8 ax = *(const half8*)((const _Float16*)xsB + am * WS + k);
        half8 bx = *(const half8*)((const _Float16*)Xw + br * WS + k);
        aX = __builtin_amdgcn_mfma_f32_16x16x32_f16(ax, bx, aX, 0, 0, 0);
      }
      float4v acc = aH + aX;
      if (lane < 32) {
#pragma unroll
        for (int reg = 0; reg < 4; ++reg) {
          int m = (lane >> 4) * 4 + reg;
          part[w * 128 + m * 16 + (lane & 15)] = acc[reg];
        }
      }
      __syncthreads();

      float hnew = 0.f;
      if (tid < 128) {
        int o = eb * 16 + ejl;
        float iv = sigf(part[0 * 128 + o] + part[4 * 128 + o] + bi_);
        float fv = sigf(part[1 * 128 + o] + part[5 * 128 + o] + bf_);
        float gv = tanhfast(part[2 * 128 + o] + part[6 * 128 + o] + bg_);
        float ov = sigf(part[3 * 128 + o] + part[7 * 128 + o] + bo_);
        float cn = fv * cvalB + iv * gv;
        float hn = ov * tanhfast(cn);
        hnew = hn * mvalB + h0vB * (1.f - mvalB);
        cvalB = cn * mvalB + h0vB * (1.f - mvalB);
      }
      {
        int mb = (tid < 128) ? (int)f2h(hnew) : 0;
        int n1 = __shfl_down(mb, 1, 64), n2 = __shfl_down(mb, 2, 64), n3 = __shfl_down(mb, 3, 64);
        if (tid < 128 && ((ejl & 3) == 0)) {
          unsigned long long u = ((unsigned long long)(((unsigned)n2) | ((unsigned)n3 << 16)) << 32) |
                                 (((unsigned)mb) | ((unsigned)n1 << 16));
          AT_ST64(nxt + bglobB * 128 + (jglob >> 2), u);
        }
      }
      __syncthreads();
      if (tid == 0) AT_ST_I(&slotsB[rank], ts + 2);

      ((unsigned*)xsB)[xr0r * (WS / 2) + xc] = pk2h(a0.x, a0.y);
      ((unsigned*)xsB)[xr1r * (WS / 2) + xc] = pk2h(a1.x, a1.y);
      ((unsigned*)xsB)[xr2r * (WS / 2) + xc] = pk2h(a2.x, a2.y);
      ((unsigned*)xsB)[xr3r * (WS / 2) + xc] = pk2h(a3.x, a3.y);
      if (tid < 128) {
        out[((size_t)ts * B_DIM + bglobB) * H_DIM + jglob] = hnew;
        if (ts == T_DIM - 1) {
          out[(size_t)T_DIM * B_DIM * H_DIM + bglobB * H_DIM + jglob] = hnew;
          out[(size_t)T_DIM * B_DIM * H_DIM + B_DIM * H_DIM + bglobB * H_DIM + jglob] = cvalB;
        } else {
          mvalB = mask[(ts + 1) * B_DIM + bglobB];
        }
      }
    }
  }
}

// ---------------------------------------------------------------- launch
extern "C" void kernel_launch(void* const* d_in, const int* in_sizes, int n_in,
                              void* d_out, int out_size, void* d_ws, size_t ws_size,
                              hipStream_t stream) {
  const float* inputs = (const float*)d_in[0];
  const float* maskp  = (const float*)d_in[1];
  const float* h0     = (const float*)d_in[2];
  const float* W_ih   = (const float*)d_in[3];
  const float* W_hh   = (const float*)d_in[4];
  const float* b_ih   = (const float*)d_in[5];
  const float* b_hh   = (const float*)d_in[6];
  float* out = (float*)d_out;

  char* ws = (char*)d_ws;
  int* slot_base = (int*)ws;                            // 8 groups x 32 slots (128B apart)
  unsigned short* hbuf = (unsigned short*)(ws + 4096);  // fp16 h double buffer, 128KB

  (void)hipMemsetAsync(d_ws, 0, 4096, stream);

  size_t ldsB = (size_t)(64 * WS * 2 * 2 + 3 * 8 * WS * 2 + 8 * 128 * 4);  // 162,176 B

  lstm_seq<<<NBLK, NTHR, ldsB, stream>>>(inputs, maskp, h0, W_hh, W_ih, b_ih, b_hh,
                                         out, hbuf, slot_base);

  (void)in_sizes; (void)n_in; (void)out_size; (void)ws_size;
}